// Round 1
// baseline (7206.094 us; speedup 1.0000x reference)
//
#include <hip/hip_runtime.h>
#include <math.h>

// Problem constants (from reference)
#define TT   16
#define BATCH 8
#define CIN  16
#define HH   64
#define WW   64
#define HWSZ 4096          // 64*64
#define HID  32

// Fused ConvLSTM step: 3x3 SAME conv over concat(xin, h_prev) -> 4*HID gates,
// then LSTM pointwise. One dispatch per (timestep, layer).
//
// Block: 64x4 threads -> spatial tile 64 wide x 4 tall (full row width).
// blockIdx.x = y-tile (0..15), blockIdx.y = out-channel group of 8 (0..3),
// blockIdx.z = batch (0..7).
//
// CIN_L = XC + HID input channels; XC channels come from xin, HID from hprev.
template<int CIN_L, int XC>
__global__ __launch_bounds__(256)
void lstm_step(const float* __restrict__ xin,    // [B, XC, H, W]
               const float* __restrict__ hprev,  // [B, HID, H, W] (unused if t0)
               const float* __restrict__ wgt,    // [4*HID, CIN_L, 3, 3]
               const float* __restrict__ bias,   // [4*HID]
               float* __restrict__ cbuf,         // [B, HID, H, W] running c (in/out)
               float* __restrict__ hout,         // [B, HID, H, W] h_seq[t]
               float* __restrict__ hT,           // also write h here if non-null
               int t0)                           // 1 => h_prev = c_prev = 0
{
    constexpr int CHUNK = 8;     // input channels staged per LDS pass
    constexpr int TLW = 66;      // tile width with halo
    constexpr int TLH = 6;       // tile height with halo
    __shared__ float lds[CHUNK][TLH][TLW];   // 12.7 KB

    const int tx = threadIdx.x;      // 0..63  (x within row)
    const int ty = threadIdx.y;      // 0..3   (y within tile)
    const int tid = ty * 64 + tx;
    const int tileY = blockIdx.x;    // rows [tileY*4, tileY*4+4)
    const int chg  = blockIdx.y;     // out channels [chg*8, chg*8+8)
    const int b    = blockIdx.z;

    const int y = tileY * 4 + ty;
    const int x = tx;

    // 8 out-channels x 4 gates accumulators, init = bias (wave-uniform loads)
    float acc[8][4];
#pragma unroll
    for (int ch = 0; ch < 8; ++ch)
#pragma unroll
        for (int g = 0; g < 4; ++g)
            acc[ch][g] = bias[g * HID + chg * 8 + ch];

    for (int c0 = 0; c0 < CIN_L; c0 += CHUNK) {
        // ---- stage CHUNK input planes' (66 x 6) halo tile into LDS ----
        for (int idx = tid; idx < CHUNK * TLH * TLW; idx += 256) {
            const int c  = idx / (TLH * TLW);
            const int r  = idx % (TLH * TLW);
            const int py = r / TLW;
            const int px = r % TLW;
            const int gy = tileY * 4 + py - 1;
            const int gx = px - 1;
            const int cc = c0 + c;
            float v = 0.f;
            if (gy >= 0 && gy < HH && gx >= 0 && gx < WW) {
                if (cc < XC) {
                    v = xin[((size_t)(b * XC + cc) * HH + gy) * WW + gx];
                } else if (!t0) {
                    v = hprev[((size_t)(b * HID + (cc - XC)) * HH + gy) * WW + gx];
                }
            }
            ((float*)lds)[idx] = v;
        }
        __syncthreads();

        // ---- accumulate CHUNK input channels ----
#pragma unroll
        for (int c = 0; c < CHUNK; ++c) {
            float v[9];
#pragma unroll
            for (int ky = 0; ky < 3; ++ky)
#pragma unroll
                for (int kx = 0; kx < 3; ++kx)
                    v[ky * 3 + kx] = lds[c][ty + ky][tx + kx];

            const int cin = c0 + c;
#pragma unroll
            for (int ch = 0; ch < 8; ++ch) {
#pragma unroll
                for (int g = 0; g < 4; ++g) {
                    // wave-uniform weight pointer -> scalar loads (9 contiguous)
                    const float* wp =
                        wgt + ((size_t)(g * HID + chg * 8 + ch) * CIN_L + cin) * 9;
                    float a = acc[ch][g];
#pragma unroll
                    for (int k = 0; k < 9; ++k)
                        a = fmaf(v[k], wp[k], a);
                    acc[ch][g] = a;
                }
            }
        }
        __syncthreads();
    }

    // ---- LSTM pointwise epilogue ----
    const bool writeT = (hT != nullptr);
#pragma unroll
    for (int ch = 0; ch < 8; ++ch) {
        const int cho = chg * 8 + ch;
        const size_t oi = ((size_t)(b * HID + cho) * HH + y) * WW + x;
        const float cp = t0 ? 0.f : cbuf[oi];
        const float ig = 1.f / (1.f + __expf(-acc[ch][0]));
        const float fg = 1.f / (1.f + __expf(-acc[ch][1]));
        const float og = 1.f / (1.f + __expf(-acc[ch][2]));
        const float gg = tanhf(acc[ch][3]);
        const float cn = fg * cp + ig * gg;
        const float hn = og * tanhf(cn);
        cbuf[oi] = cn;
        hout[oi] = hn;
        if (writeT) hT[oi] = hn;
    }
}

extern "C" void kernel_launch(void* const* d_in, const int* in_sizes, int n_in,
                              void* d_out, int out_size, void* d_ws, size_t ws_size,
                              hipStream_t stream) {
    const float* x  = (const float*)d_in[0];   // [16, 8, 16, 64, 64]
    const float* W0 = (const float*)d_in[1];   // [128, 48, 3, 3]
    const float* b0 = (const float*)d_in[2];   // [128]
    const float* W1 = (const float*)d_in[3];   // [128, 64, 3, 3]
    const float* b1 = (const float*)d_in[4];   // [128]
    float* out = (float*)d_out;

    // d_out layout (flat, return order):
    // h_seq0 [16,8,32,64,64] | h_seq1 [16,8,32,64,64] | h0_T | c0_T | h1_T | c1_T
    float* hseq0 = out;                          // 16,777,216 elems
    float* hseq1 = out + 16777216;               // 16,777,216 elems
    float* h0T   = out + 33554432;               // 1,048,576 elems
    float* c0T   = out + 34603008;               // running c for layer 0
    float* h1T   = out + 35651584;
    float* c1T   = out + 36700160;               // running c for layer 1

    const dim3 blk(64, 4, 1);
    const dim3 grd(16, 4, BATCH);                // 512 blocks/dispatch
    const size_t xstep = (size_t)BATCH * CIN * HWSZ;  // 524,288
    const size_t hstep = (size_t)BATCH * HID * HWSZ;  // 1,048,576

    for (int t = 0; t < TT; ++t) {
        // Layer 0: input = x[t] (16 ch) + h_seq0[t-1] (32 ch)
        lstm_step<48, 16><<<grd, blk, 0, stream>>>(
            x + (size_t)t * xstep,
            t ? hseq0 + (size_t)(t - 1) * hstep : nullptr,
            W0, b0, c0T,
            hseq0 + (size_t)t * hstep,
            (t == TT - 1) ? h0T : nullptr,
            (t == 0) ? 1 : 0);

        // Layer 1: input = h_seq0[t] (32 ch) + h_seq1[t-1] (32 ch)
        lstm_step<64, 32><<<grd, blk, 0, stream>>>(
            hseq0 + (size_t)t * hstep,
            t ? hseq1 + (size_t)(t - 1) * hstep : nullptr,
            W1, b1, c1T,
            hseq1 + (size_t)t * hstep,
            (t == TT - 1) ? h1T : nullptr,
            (t == 0) ? 1 : 0);
    }
}

// Round 2
// 3499.420 us; speedup vs baseline: 2.0592x; 2.0592x over previous
//
#include <hip/hip_runtime.h>
#include <math.h>

// Problem constants (from reference)
#define TT   16
#define BATCH 8
#define CIN  16
#define HH   64
#define WW   64
#define HWSZ 4096          // 64*64
#define HID  32

// Fused ConvLSTM step v2: 3x3 SAME conv over concat(xin, h_prev) -> 4*HID
// gates, then LSTM pointwise. One dispatch per (timestep, layer).
//
// v2 changes vs v1 (which was s_load-latency-bound, VALUBusy 15%):
//  - 2 pixels/thread (adjacent rows) -> each weight feeds 2 FMAs
//  - weights read as contiguous 36-float blocks (cin-chunk inner) -> wide s_loads
//  - 8 gate-channels (2 ch x 4 gates) per block -> 1024 blocks, 16 waves/CU
//
// Block: (64,4) threads. Pixel tile: 64 wide x 8 tall; thread (tx,ty) owns
// pixels (tx, y0) and (tx, y0+1) with y0 = tileY*8 + ty*2.
// blockIdx.x = y-tile (0..7), blockIdx.y = ch-pair (0..15), blockIdx.z = batch.
template<int CIN_L, int XC>
__global__ __launch_bounds__(256)
void lstm_step(const float* __restrict__ xin,    // [B, XC, H, W]
               const float* __restrict__ hprev,  // [B, HID, H, W] (unused if t0)
               const float* __restrict__ wgt,    // [4*HID, CIN_L, 3, 3]
               const float* __restrict__ bias,   // [4*HID]
               float* __restrict__ cbuf,         // [B, HID, H, W] running c (in/out)
               float* __restrict__ hout,         // [B, HID, H, W] h_seq[t]
               float* __restrict__ hT,           // also write h here if non-null
               int t0)                           // 1 => h_prev = c_prev = 0
{
    constexpr int CHUNK = 4;     // input channels staged per LDS pass
    constexpr int TLW = 66;      // tile width with halo
    constexpr int TLH = 10;      // 8 rows + halo
    constexpr int TLN = CHUNK * TLH * TLW;     // 2640
    __shared__ float lds[CHUNK][TLH][TLW];     // 10.3 KB

    const int tx = threadIdx.x;      // 0..63
    const int ty = threadIdx.y;      // 0..3
    const int tid = ty * 64 + tx;
    const int tileY = blockIdx.x;    // rows [tileY*8, tileY*8+8)
    const int chp  = blockIdx.y;     // output channels {chp*2, chp*2+1}
    const int b    = blockIdx.z;

    const int y0 = tileY * 8 + ty * 2;   // first of the 2 pixel rows
    const int x = tx;

    // acc[ch][gate][pix]
    float acc[2][4][2];
#pragma unroll
    for (int ch = 0; ch < 2; ++ch)
#pragma unroll
        for (int g = 0; g < 4; ++g) {
            const float bv = bias[g * HID + chp * 2 + ch];
            acc[ch][g][0] = bv;
            acc[ch][g][1] = bv;
        }

    for (int c0 = 0; c0 < CIN_L; c0 += CHUNK) {
        // ---- stage CHUNK input planes' (66 x 10) halo tile into LDS ----
        for (int idx = tid; idx < TLN; idx += 256) {
            const int c  = idx / (TLH * TLW);
            const int r  = idx % (TLH * TLW);
            const int py = r / TLW;
            const int px = r % TLW;
            const int gy = tileY * 8 + py - 1;
            const int gx = px - 1;
            const int cc = c0 + c;
            float v = 0.f;
            if (gy >= 0 && gy < HH && gx >= 0 && gx < WW) {
                if (cc < XC) {
                    v = xin[((size_t)(b * XC + cc) * HH + gy) * WW + gx];
                } else if (!t0) {
                    v = hprev[((size_t)(b * HID + (cc - XC)) * HH + gy) * WW + gx];
                }
            }
            ((float*)lds)[idx] = v;
        }
        __syncthreads();

        // ---- pixel windows into registers: rows y0-1..y0+2, cols x-1..x+1 ----
        // lds[c][py][px] holds global (gy = tileY*8 + py - 1, gx = px - 1), so
        // window row (y0-1+r) -> py = ty*2 + r; window col (x-1+cc) -> px = tx+cc.
        float v[CHUNK][4][3];
#pragma unroll
        for (int c = 0; c < CHUNK; ++c)
#pragma unroll
            for (int r = 0; r < 4; ++r)
#pragma unroll
                for (int cc = 0; cc < 3; ++cc)
                    v[c][r][cc] = lds[c][ty * 2 + r][tx + cc];

        __syncthreads();   // values in regs; FMA phase below doesn't touch LDS

        // ---- FMA: per (ch,gate) a contiguous 36-float weight block ----
#pragma unroll
        for (int ch = 0; ch < 2; ++ch) {
#pragma unroll
            for (int g = 0; g < 4; ++g) {
                const float* wp =
                    wgt + ((size_t)(g * HID + chp * 2 + ch) * CIN_L + c0) * 9;
                float a0 = acc[ch][g][0];
                float a1 = acc[ch][g][1];
#pragma unroll
                for (int c = 0; c < CHUNK; ++c) {
#pragma unroll
                    for (int ky = 0; ky < 3; ++ky) {
#pragma unroll
                        for (int kx = 0; kx < 3; ++kx) {
                            const float w = wp[c * 9 + ky * 3 + kx];
                            a0 = fmaf(v[c][ky][kx],     w, a0);
                            a1 = fmaf(v[c][ky + 1][kx], w, a1);
                        }
                    }
                }
                acc[ch][g][0] = a0;
                acc[ch][g][1] = a1;
            }
        }
    }

    // ---- LSTM pointwise epilogue (2 ch x 2 pixels) ----
    const bool writeT = (hT != nullptr);
#pragma unroll
    for (int ch = 0; ch < 2; ++ch) {
        const int cho = chp * 2 + ch;
#pragma unroll
        for (int p = 0; p < 2; ++p) {
            const size_t oi = ((size_t)(b * HID + cho) * HH + (y0 + p)) * WW + x;
            const float cp = t0 ? 0.f : cbuf[oi];
            const float ig = 1.f / (1.f + __expf(-acc[ch][0][p]));
            const float fg = 1.f / (1.f + __expf(-acc[ch][1][p]));
            const float og = 1.f / (1.f + __expf(-acc[ch][2][p]));
            const float gg = tanhf(acc[ch][3][p]);
            const float cn = fg * cp + ig * gg;
            const float hn = og * tanhf(cn);
            cbuf[oi] = cn;
            hout[oi] = hn;
            if (writeT) hT[oi] = hn;
        }
    }
}

extern "C" void kernel_launch(void* const* d_in, const int* in_sizes, int n_in,
                              void* d_out, int out_size, void* d_ws, size_t ws_size,
                              hipStream_t stream) {
    const float* x  = (const float*)d_in[0];   // [16, 8, 16, 64, 64]
    const float* W0 = (const float*)d_in[1];   // [128, 48, 3, 3]
    const float* b0 = (const float*)d_in[2];   // [128]
    const float* W1 = (const float*)d_in[3];   // [128, 64, 3, 3]
    const float* b1 = (const float*)d_in[4];   // [128]
    float* out = (float*)d_out;

    // d_out layout (flat, return order):
    // h_seq0 [16,8,32,64,64] | h_seq1 [16,8,32,64,64] | h0_T | c0_T | h1_T | c1_T
    float* hseq0 = out;                          // 16,777,216 elems
    float* hseq1 = out + 16777216;               // 16,777,216 elems
    float* h0T   = out + 33554432;               // 1,048,576 elems
    float* c0T   = out + 34603008;               // running c for layer 0
    float* h1T   = out + 35651584;
    float* c1T   = out + 36700160;               // running c for layer 1

    const dim3 blk(64, 4, 1);
    const dim3 grd(8, 16, BATCH);                // 1024 blocks/dispatch
    const size_t xstep = (size_t)BATCH * CIN * HWSZ;  // 524,288
    const size_t hstep = (size_t)BATCH * HID * HWSZ;  // 1,048,576

    for (int t = 0; t < TT; ++t) {
        // Layer 0: input = x[t] (16 ch) + h_seq0[t-1] (32 ch)
        lstm_step<48, 16><<<grd, blk, 0, stream>>>(
            x + (size_t)t * xstep,
            t ? hseq0 + (size_t)(t - 1) * hstep : nullptr,
            W0, b0, c0T,
            hseq0 + (size_t)t * hstep,
            (t == TT - 1) ? h0T : nullptr,
            (t == 0) ? 1 : 0);

        // Layer 1: input = h_seq0[t] (32 ch) + h_seq1[t-1] (32 ch)
        lstm_step<64, 32><<<grd, blk, 0, stream>>>(
            hseq0 + (size_t)t * hstep,
            t ? hseq1 + (size_t)(t - 1) * hstep : nullptr,
            W1, b1, c1T,
            hseq1 + (size_t)t * hstep,
            (t == TT - 1) ? h1T : nullptr,
            (t == 0) ? 1 : 0);
    }
}

// Round 3
// 443.301 us; speedup vs baseline: 16.2555x; 7.8940x over previous
//
#include <hip/hip_runtime.h>
#include <math.h>

#define TT   16
#define BATCH 8
#define HH   64
#define WW   64
#define HWSZ 4096
#define HID  32

typedef __bf16 bf16x8 __attribute__((ext_vector_type(8)));
typedef float  f32x4  __attribute__((ext_vector_type(4)));
typedef unsigned short u16;
typedef unsigned int   u32;

__device__ __forceinline__ u16 f2bf(float f) {
    union { float f; u32 u; } v; v.f = f;
    u32 r = v.u + 0x7FFF + ((v.u >> 16) & 1);   // RNE
    return (u16)(r >> 16);
}

// ---- prep: x [T,B,16,H,W] fp32 -> xbf [T*B*4096 pixels][16 cin] bf16 ----
__global__ __launch_bounds__(256)
void prep_x(const float* __restrict__ x, u16* __restrict__ xbf) {
    const int p = blockIdx.x * 256 + threadIdx.x;   // (t*8+b)*4096 + pix
    const int tb = p >> 12, pix = p & 4095;
    const float* src = x + ((size_t)tb * 16) * HWSZ + pix;
    u16 o[16];
#pragma unroll
    for (int c = 0; c < 16; ++c) o[c] = f2bf(src[(size_t)c * HWSZ]);
    uint4* dst = (uint4*)(xbf + (size_t)p * 16);
    dst[0] = *(uint4*)&o[0];
    dst[1] = *(uint4*)&o[8];
}

// ---- prep: W [128,CIN_L,3,3] fp32 -> MFMA B-frag order [tap][kc][nt][lane][8] bf16
__global__ __launch_bounds__(256)
void prep_w(const float* __restrict__ W, u16* __restrict__ wf, int cinl) {
    const int idx = blockIdx.x * 256 + threadIdx.x;   // [0, 9216)
    const int lane = idx & 63, nt = (idx >> 6) & 7, kc = (idx >> 9) & 1, tap = idx >> 10;
    const int cho = nt * 16 + (lane & 15);
    const int cb  = kc * 32 + ((lane >> 4) * 8);
    u16 o[8];
#pragma unroll
    for (int j = 0; j < 8; ++j) {
        const int cin = cb + j;
        o[j] = (cin < cinl) ? f2bf(W[((size_t)cho * cinl + cin) * 9 + tap]) : (u16)0;
    }
    ((uint4*)wf)[idx] = *(uint4*)&o[0];
}

// ---- fused ConvLSTM step: one layer-step per block-half ----
// blk in [0,512): y0 = blk&63, b = blk>>6. Block = 4 waves; wave tile M=32,N=64
// (n-tiles {khalf, khalf+2, khalf+4, khalf+6} = 4 gates of one c-half).
__device__ __forceinline__ void conv_step(
    const u16* __restrict__ srcX, int xch,          // pixel-major bf16 [B*4096][xch]
    const u16* __restrict__ srcH,                   // pixel-major bf16 [B*4096][32]
    const uint4* __restrict__ wf,                   // [9][2][8][64] x 16B
    const float* __restrict__ bias,                 // [128]
    float* __restrict__ cbuf, float* __restrict__ hout,
    float* __restrict__ hT, u16* __restrict__ hbfo,
    int t0, int blk, uint4* lds4)
{
    const int tid = threadIdx.x;
    const int y0 = blk & 63;
    const int b  = blk >> 6;

    // ---- stage 3 rows x 66 px x 64 cin (16B chunks), XOR-swizzled ----
    for (int q = tid; q < 1584; q += 256) {
        const int c8 = q & 7;
        const int pr = q >> 3;          // 0..197
        const int px = pr % 66;
        const int r  = pr / 66;
        const int gy = y0 - 1 + r;
        const int gx = px - 1;
        uint4 v = {0u, 0u, 0u, 0u};
        if (gy >= 0 && gy < HH && gx >= 0 && gx < WW) {
            const int pix = b * HWSZ + gy * WW + gx;
            const int cin8 = c8 * 8;
            if (cin8 < xch) {
                v = *(const uint4*)(srcX + (size_t)pix * xch + cin8);
            } else if (cin8 < xch + 32) {
                if (!t0) v = *(const uint4*)(srcH + (size_t)pix * 32 + (cin8 - xch));
            }
        }
        lds4[(pr * 8 + c8) ^ (px & 7)] = v;
    }
    __syncthreads();

    const int lane  = tid & 63;
    const int w     = tid >> 6;
    const int l15   = lane & 15, lhi = lane >> 4;
    const int khalf = w & 1;
    const int pbase = (w >> 1) * 32;

    float bv[4];
#pragma unroll
    for (int n = 0; n < 4; ++n) bv[n] = bias[n * 32 + khalf * 16 + l15];
    f32x4 acc[2][4];
#pragma unroll
    for (int m = 0; m < 2; ++m)
#pragma unroll
        for (int n = 0; n < 4; ++n)
            acc[m][n] = (f32x4){bv[n], bv[n], bv[n], bv[n]};

    const int p0 = pbase + l15 + 1;   // tile px for dx=0
#pragma unroll
    for (int tap = 0; tap < 9; ++tap) {
        const int r  = tap / 3;        // 1 + dy
        const int dx = tap % 3 - 1;
#pragma unroll
        for (int kc = 0; kc < 2; ++kc) {
            const int kcell = kc * 4 + lhi;
            bf16x8 a[2];
#pragma unroll
            for (int m = 0; m < 2; ++m) {
                const int pxt = p0 + m * 16 + dx;
                a[m] = __builtin_bit_cast(bf16x8,
                        lds4[(((r * 66 + pxt) * 8) + kcell) ^ (pxt & 7)]);
            }
#pragma unroll
            for (int n = 0; n < 4; ++n) {
                const bf16x8 bw = __builtin_bit_cast(bf16x8,
                        wf[((tap * 2 + kc) * 8 + (khalf + 2 * n)) * 64 + lane]);
#pragma unroll
                for (int m = 0; m < 2; ++m)
                    acc[m][n] = __builtin_amdgcn_mfma_f32_16x16x32_bf16(
                                    a[m], bw, acc[m][n], 0, 0, 0);
            }
        }
    }

    // ---- LSTM pointwise epilogue ----
    const int c = khalf * 16 + l15;                     // hid channel
    const size_t cb_base = ((size_t)(b * HID + c)) * HWSZ + (size_t)y0 * WW;
    const size_t hb_base = ((size_t)b * HWSZ + (size_t)y0 * WW);
#pragma unroll
    for (int m = 0; m < 2; ++m) {
#pragma unroll
        for (int rr = 0; rr < 4; ++rr) {
            const int p = pbase + m * 16 + lhi * 4 + rr;
            const size_t oi = cb_base + p;
            const float cp = t0 ? 0.f : cbuf[oi];
            const float iv = acc[m][0][rr], fv = acc[m][1][rr];
            const float ov = acc[m][2][rr], gv = acc[m][3][rr];
            const float ig = 1.f / (1.f + __expf(-iv));
            const float fg = 1.f / (1.f + __expf(-fv));
            const float og = 1.f / (1.f + __expf(-ov));
            const float gc = fminf(fmaxf(gv, -20.f), 20.f);
            const float eg = __expf(2.f * gc);
            const float gg = (eg - 1.f) / (eg + 1.f);
            const float cn = fg * cp + ig * gg;
            const float cc = fminf(fmaxf(cn, -20.f), 20.f);
            const float ec = __expf(2.f * cc);
            const float th = (ec - 1.f) / (ec + 1.f);
            const float hn = og * th;
            cbuf[oi] = cn;
            hout[oi] = hn;
            if (hT) hT[oi] = hn;
            hbfo[(hb_base + p) * 32 + c] = f2bf(hn);
        }
    }
}

__global__ __launch_bounds__(256)
void fused_step(
    const u16* srcX0, const u16* srcH0, const uint4* wf0, const float* bias0,
    float* cbuf0, float* hout0, float* hT0, u16* hbfo0, int t00, int act0,
    const u16* srcX1, const u16* srcH1, const uint4* wf1, const float* bias1,
    float* cbuf1, float* hout1, float* hT1, u16* hbfo1, int t01, int act1)
{
    __shared__ uint4 lds4[1584];   // 25,344 B
    const int blk = blockIdx.x;
    if (blk < 512) {
        if (!act0) return;
        conv_step(srcX0, 16, srcH0, wf0, bias0, cbuf0, hout0, hT0, hbfo0, t00, blk, lds4);
    } else {
        if (!act1) return;
        conv_step(srcX1, 32, srcH1, wf1, bias1, cbuf1, hout1, hT1, hbfo1, t01, blk - 512, lds4);
    }
}

extern "C" void kernel_launch(void* const* d_in, const int* in_sizes, int n_in,
                              void* d_out, int out_size, void* d_ws, size_t ws_size,
                              hipStream_t stream) {
    const float* x  = (const float*)d_in[0];
    const float* W0 = (const float*)d_in[1];
    const float* b0 = (const float*)d_in[2];
    const float* W1 = (const float*)d_in[3];
    const float* b1 = (const float*)d_in[4];
    float* out = (float*)d_out;

    float* hseq0 = out;
    float* hseq1 = out + 16777216;
    float* h0T   = out + 33554432;
    float* c0T   = out + 34603008;
    float* h1T   = out + 35651584;
    float* c1T   = out + 36700160;

    // ws layout (bytes): xbf 16,777,216 | wf0 147,456 | wf1 147,456 |
    //                    hbf0[2] 2x2,097,152 | hbf1[2] 2x2,097,152  = 25.5 MB
    char* ws = (char*)d_ws;
    u16*  xbf = (u16*)ws;
    u16*  wf0 = (u16*)(ws + 16777216);
    u16*  wf1 = (u16*)(ws + 16777216 + 147456);
    u16*  hbf0[2] = { (u16*)(ws + 17072128), (u16*)(ws + 17072128 + 2097152) };
    u16*  hbf1[2] = { (u16*)(ws + 21266432), (u16*)(ws + 21266432 + 2097152) };

    prep_x<<<2048, 256, 0, stream>>>(x, xbf);
    prep_w<<<36, 256, 0, stream>>>(W0, wf0, 48);
    prep_w<<<36, 256, 0, stream>>>(W1, wf1, 64);

    const size_t hstep = (size_t)BATCH * HID * HWSZ;   // 1,048,576 floats
    const size_t xstep = (size_t)BATCH * HWSZ * 16;    // bf16 elems per t

    for (int d = 0; d <= TT; ++d) {
        const int t0 = (d < TT) ? d : TT - 1;      // clamped (inactive half)
        const int t1 = (d >= 1) ? d - 1 : 0;
        const int act0 = (d < TT), act1 = (d >= 1);
        fused_step<<<1024, 256, 0, stream>>>(
            // layer 0, time t0: x = xbf[t0], h_prev = hbf0[(t0-1)&1]
            xbf + (size_t)t0 * xstep, hbf0[(t0 - 1) & 1],
            (const uint4*)wf0, b0, c0T,
            hseq0 + (size_t)t0 * hstep, (t0 == TT - 1 && act0) ? h0T : nullptr,
            hbf0[t0 & 1], (t0 == 0) ? 1 : 0, act0,
            // layer 1, time t1: x = hbf0[t1&1], h_prev = hbf1[(t1-1)&1]
            hbf0[t1 & 1], hbf1[(t1 - 1) & 1],
            (const uint4*)wf1, b1, c1T,
            hseq1 + (size_t)t1 * hstep, (t1 == TT - 1 && act1) ? h1T : nullptr,
            hbf1[t1 & 1], (t1 == 0) ? 1 : 0, act1);
    }
}

// Round 4
// 431.554 us; speedup vs baseline: 16.6980x; 1.0272x over previous
//
#include <hip/hip_runtime.h>
#include <math.h>

#define TT   16
#define BATCH 8
#define HH   64
#define WW   64
#define HWSZ 4096
#define HID  32

typedef __bf16 bf16x8 __attribute__((ext_vector_type(8)));
typedef float  f32x4  __attribute__((ext_vector_type(4)));
typedef unsigned short u16;
typedef unsigned int   u32;

__device__ __forceinline__ u16 f2bf(float f) {
    union { float f; u32 u; } v; v.f = f;
    u32 r = v.u + 0x7FFF + ((v.u >> 16) & 1);   // RNE
    return (u16)(r >> 16);
}

// ---- prep: x [T,B,16,H,W] fp32 -> xbf [T*B*4096 pixels][16 cin] bf16 ----
__global__ __launch_bounds__(256)
void prep_x(const float* __restrict__ x, u16* __restrict__ xbf) {
    const int p = blockIdx.x * 256 + threadIdx.x;   // (t*8+b)*4096 + pix
    const int tb = p >> 12, pix = p & 4095;
    const float* src = x + ((size_t)tb * 16) * HWSZ + pix;
    u16 o[16];
#pragma unroll
    for (int c = 0; c < 16; ++c) o[c] = f2bf(src[(size_t)c * HWSZ]);
    uint4* dst = (uint4*)(xbf + (size_t)p * 16);
    dst[0] = *(uint4*)&o[0];
    dst[1] = *(uint4*)&o[8];
}

// ---- prep: W [128,CIN_L,3,3] fp32 -> MFMA B-frag order [tap][kc][nt][lane][8] bf16
__global__ __launch_bounds__(256)
void prep_w(const float* __restrict__ W, u16* __restrict__ wf, int cinl) {
    const int idx = blockIdx.x * 256 + threadIdx.x;   // [0, 9216)
    const int lane = idx & 63, nt = (idx >> 6) & 7, kc = (idx >> 9) & 1, tap = idx >> 10;
    const int cho = nt * 16 + (lane & 15);
    const int cb  = kc * 32 + ((lane >> 4) * 8);
    u16 o[8];
#pragma unroll
    for (int j = 0; j < 8; ++j) {
        const int cin = cb + j;
        o[j] = (cin < cinl) ? f2bf(W[((size_t)cho * cinl + cin) * 9 + tap]) : (u16)0;
    }
    ((uint4*)wf)[idx] = *(uint4*)&o[0];
}

// ---- fused ConvLSTM step v4 ----
// Per layer-half: 256 blocks; blk -> b = blk>>5, y0 = (blk&31)*2 (2 output rows).
// Block = 4 waves: wave w -> row (w>>1), khalf (w&1). Wave tile M=64 px x N=64 ch
// (4 m-frags x 4 gate-ntiles). Each weight frag feeds 4 MFMAs (was 2 in v3).
__device__ __forceinline__ void conv_step(
    const u16* __restrict__ srcX, int xch,          // pixel-major bf16 [B*4096][xch]
    const u16* __restrict__ srcH,                   // pixel-major bf16 [B*4096][32]
    const uint4* __restrict__ wf,                   // [9][2][8][64] x 16B
    const float* __restrict__ bias,                 // [128]
    float* __restrict__ cbuf, float* __restrict__ hout,
    float* __restrict__ hT, u16* __restrict__ hbfo,
    int t0, int blk, uint4* lds4)
{
    const int tid = threadIdx.x;
    const int y0 = (blk & 31) * 2;
    const int b  = blk >> 5;

    // ---- stage 4 rows x 66 px x 64 cin (16B chunks), XOR-swizzled ----
    for (int q = tid; q < 2112; q += 256) {
        const int c8 = q & 7;
        const int pr = q >> 3;          // 0..263
        const int px = pr % 66;
        const int r  = pr / 66;         // 0..3  (gy = y0-1+r)
        const int gy = y0 - 1 + r;
        const int gx = px - 1;
        uint4 v = {0u, 0u, 0u, 0u};
        if (gy >= 0 && gy < HH && gx >= 0 && gx < WW) {
            const int pix = b * HWSZ + gy * WW + gx;
            const int cin8 = c8 * 8;
            if (cin8 < xch) {
                v = *(const uint4*)(srcX + (size_t)pix * xch + cin8);
            } else if (cin8 < xch + 32) {
                if (!t0) v = *(const uint4*)(srcH + (size_t)pix * 32 + (cin8 - xch));
            }
        }
        lds4[(pr * 8 + c8) ^ (px & 7)] = v;
    }
    __syncthreads();

    const int lane  = tid & 63;
    const int w     = tid >> 6;
    const int l15   = lane & 15, lhi = lane >> 4;
    const int khalf = w & 1;
    const int wrow  = w >> 1;           // which of the 2 output rows

    float bv[4];
#pragma unroll
    for (int n = 0; n < 4; ++n) bv[n] = bias[n * 32 + khalf * 16 + l15];
    f32x4 acc[4][4];
#pragma unroll
    for (int m = 0; m < 4; ++m)
#pragma unroll
        for (int n = 0; n < 4; ++n)
            acc[m][n] = (f32x4){bv[n], bv[n], bv[n], bv[n]};

    const int p0 = l15 + 1;   // tile px for dx=0, m=0
#pragma unroll
    for (int tap = 0; tap < 9; ++tap) {
        const int sr = wrow + tap / 3;  // staged row index for this ky
        const int dx = tap % 3 - 1;
#pragma unroll
        for (int kc = 0; kc < 2; ++kc) {
            const int kcell = kc * 4 + lhi;
            bf16x8 a[4];
#pragma unroll
            for (int m = 0; m < 4; ++m) {
                const int pxt = p0 + m * 16 + dx;
                a[m] = __builtin_bit_cast(bf16x8,
                        lds4[(((sr * 66 + pxt) * 8) + kcell) ^ (pxt & 7)]);
            }
#pragma unroll
            for (int n = 0; n < 4; ++n) {
                const bf16x8 bw = __builtin_bit_cast(bf16x8,
                        wf[((tap * 2 + kc) * 8 + (khalf + 2 * n)) * 64 + lane]);
#pragma unroll
                for (int m = 0; m < 4; ++m)
                    acc[m][n] = __builtin_amdgcn_mfma_f32_16x16x32_bf16(
                                    a[m], bw, acc[m][n], 0, 0, 0);
            }
        }
    }

    // ---- LSTM pointwise epilogue ----
    const int c = khalf * 16 + l15;                     // hid channel
    const int y = y0 + wrow;
    const size_t cb_base = ((size_t)(b * HID + c)) * HWSZ + (size_t)y * WW;
    const size_t hb_base = ((size_t)b * HWSZ + (size_t)y * WW);
#pragma unroll
    for (int m = 0; m < 4; ++m) {
#pragma unroll
        for (int rr = 0; rr < 4; ++rr) {
            const int p = m * 16 + lhi * 4 + rr;
            const size_t oi = cb_base + p;
            const float cp = t0 ? 0.f : cbuf[oi];
            const float iv = acc[m][0][rr], fv = acc[m][1][rr];
            const float ov = acc[m][2][rr], gv = acc[m][3][rr];
            const float ig = 1.f / (1.f + __expf(-iv));
            const float fg = 1.f / (1.f + __expf(-fv));
            const float og = 1.f / (1.f + __expf(-ov));
            const float gc = fminf(fmaxf(gv, -20.f), 20.f);
            const float eg = __expf(2.f * gc);
            const float gg = (eg - 1.f) / (eg + 1.f);
            const float cn = fg * cp + ig * gg;
            const float cc = fminf(fmaxf(cn, -20.f), 20.f);
            const float ec = __expf(2.f * cc);
            const float th = (ec - 1.f) / (ec + 1.f);
            const float hn = og * th;
            cbuf[oi] = cn;
            hout[oi] = hn;
            if (hT) hT[oi] = hn;
            hbfo[(hb_base + p) * 32 + c] = f2bf(hn);
        }
    }
}

__global__ __launch_bounds__(256, 2)
void fused_step(
    const u16* srcX0, const u16* srcH0, const uint4* wf0, const float* bias0,
    float* cbuf0, float* hout0, float* hT0, u16* hbfo0, int t00, int act0,
    const u16* srcX1, const u16* srcH1, const uint4* wf1, const float* bias1,
    float* cbuf1, float* hout1, float* hT1, u16* hbfo1, int t01, int act1)
{
    __shared__ uint4 lds4[2112];   // 33,792 B
    const int blk = blockIdx.x;
    if (blk < 256) {
        if (!act0) return;
        conv_step(srcX0, 16, srcH0, wf0, bias0, cbuf0, hout0, hT0, hbfo0, t00, blk, lds4);
    } else {
        if (!act1) return;
        conv_step(srcX1, 32, srcH1, wf1, bias1, cbuf1, hout1, hT1, hbfo1, t01, blk - 256, lds4);
    }
}

extern "C" void kernel_launch(void* const* d_in, const int* in_sizes, int n_in,
                              void* d_out, int out_size, void* d_ws, size_t ws_size,
                              hipStream_t stream) {
    const float* x  = (const float*)d_in[0];
    const float* W0 = (const float*)d_in[1];
    const float* b0 = (const float*)d_in[2];
    const float* W1 = (const float*)d_in[3];
    const float* b1 = (const float*)d_in[4];
    float* out = (float*)d_out;

    float* hseq0 = out;
    float* hseq1 = out + 16777216;
    float* h0T   = out + 33554432;
    float* c0T   = out + 34603008;   // running c, layer 0 (channel-major)
    float* h1T   = out + 35651584;
    float* c1T   = out + 36700160;   // running c, layer 1

    // ws layout (bytes): xbf 16,777,216 | wf0 147,456 | wf1 147,456 |
    //                    hbf0[2] 2x2,097,152 | hbf1[2] 2x2,097,152  = 25.5 MB
    char* ws = (char*)d_ws;
    u16*  xbf = (u16*)ws;
    u16*  wf0 = (u16*)(ws + 16777216);
    u16*  wf1 = (u16*)(ws + 16777216 + 147456);
    u16*  hbf0[2] = { (u16*)(ws + 17072128), (u16*)(ws + 17072128 + 2097152) };
    u16*  hbf1[2] = { (u16*)(ws + 21266432), (u16*)(ws + 21266432 + 2097152) };

    prep_x<<<2048, 256, 0, stream>>>(x, xbf);
    prep_w<<<36, 256, 0, stream>>>(W0, wf0, 48);
    prep_w<<<36, 256, 0, stream>>>(W1, wf1, 64);

    const size_t hstep = (size_t)BATCH * HID * HWSZ;   // 1,048,576 floats
    const size_t xstep = (size_t)BATCH * HWSZ * 16;    // bf16 elems per t

    for (int d = 0; d <= TT; ++d) {
        const int t0 = (d < TT) ? d : TT - 1;      // clamped (inactive half)
        const int t1 = (d >= 1) ? d - 1 : 0;
        const int act0 = (d < TT), act1 = (d >= 1);
        fused_step<<<512, 256, 0, stream>>>(
            // layer 0, time t0: x = xbf[t0], h_prev = hbf0[(t0-1)&1]
            xbf + (size_t)t0 * xstep, hbf0[(t0 - 1) & 1],
            (const uint4*)wf0, b0, c0T,
            hseq0 + (size_t)t0 * hstep, (t0 == TT - 1 && act0) ? h0T : nullptr,
            hbf0[t0 & 1], (t0 == 0) ? 1 : 0, act0,
            // layer 1, time t1: x = hbf0[t1&1], h_prev = hbf1[(t1-1)&1]
            hbf0[t1 & 1], hbf1[(t1 - 1) & 1],
            (const uint4*)wf1, b1, c1T,
            hseq1 + (size_t)t1 * hstep, (t1 == TT - 1 && act1) ? h1T : nullptr,
            hbf1[t1 & 1], (t1 == 0) ? 1 : 0, act1);
    }
}

// Round 5
// 326.780 us; speedup vs baseline: 22.0518x; 1.3206x over previous
//
#include <hip/hip_runtime.h>
#include <math.h>

#define TT   16
#define BATCH 8
#define HH   64
#define WW   64
#define HWSZ 4096
#define HID  32

typedef __bf16 bf16x8 __attribute__((ext_vector_type(8)));
typedef float  f32x4  __attribute__((ext_vector_type(4)));
typedef unsigned short u16;
typedef unsigned int   u32;

__device__ __forceinline__ u16 f2bf(float f) {
    union { float f; u32 u; } v; v.f = f;
    u32 r = v.u + 0x7FFF + ((v.u >> 16) & 1);   // RNE
    return (u16)(r >> 16);
}

// ---- prep: x [T,B,16,H,W] fp32 -> xbf [T*B*4096 pixels][16 cin] bf16 ----
__global__ __launch_bounds__(256)
void prep_x(const float* __restrict__ x, u16* __restrict__ xbf) {
    const int p = blockIdx.x * 256 + threadIdx.x;   // (t*8+b)*4096 + pix
    const int tb = p >> 12, pix = p & 4095;
    const float* src = x + ((size_t)tb * 16) * HWSZ + pix;
    u16 o[16];
#pragma unroll
    for (int c = 0; c < 16; ++c) o[c] = f2bf(src[(size_t)c * HWSZ]);
    uint4* dst = (uint4*)(xbf + (size_t)p * 16);
    dst[0] = *(uint4*)&o[0];
    dst[1] = *(uint4*)&o[8];
}

// ---- prep: W [128,CIN_L,3,3] fp32 -> MFMA B-frag order [tap][kc][nt][lane][8] bf16
__global__ __launch_bounds__(256)
void prep_w(const float* __restrict__ W, u16* __restrict__ wf, int cinl) {
    const int idx = blockIdx.x * 256 + threadIdx.x;   // [0, 9216)
    const int lane = idx & 63, nt = (idx >> 6) & 7, kc = (idx >> 9) & 1, tap = idx >> 10;
    const int cho = nt * 16 + (lane & 15);
    const int cb  = kc * 32 + ((lane >> 4) * 8);
    u16 o[8];
#pragma unroll
    for (int j = 0; j < 8; ++j) {
        const int cin = cb + j;
        o[j] = (cin < cinl) ? f2bf(W[((size_t)cho * cinl + cin) * 9 + tap]) : (u16)0;
    }
    ((uint4*)wf)[idx] = *(uint4*)&o[0];
}

// ---- fused ConvLSTM step v5 ----
// Per layer-half: 256 blocks; blk -> b = blk>>5, y0 = (blk&31)*2 (2 output rows).
// Block = 4 waves: wave w -> row (w>>1), khalf (w&1). Wave tile M=64 px x N=64 ch.
// v5: epilogue I/O via LDS transpose -> fully coalesced dwordx4 global traffic
// (v4 was TA-transaction-bound: scalar 4B ops at 16KB lane stride = 64 lines/instr).
#define CT_STRIDE 68   // floats per (y,c) row in transpose tiles (bank-stagger)

__device__ __forceinline__ void conv_step(
    const u16* __restrict__ srcX, int xch,          // pixel-major bf16 [B*4096][xch]
    const u16* __restrict__ srcH,                   // pixel-major bf16 [B*4096][32]
    const uint4* __restrict__ wf,                   // [9][2][8][64] x 16B
    const float* __restrict__ bias,                 // [128]
    float* __restrict__ cbuf,                       // [B,32,H,W] running c (in/out)
    float* __restrict__ hout, float* __restrict__ hT,
    u16* __restrict__ hbfo,
    int t0, int blk, uint4* lds4, float* ctile)
{
    const int tid = threadIdx.x;
    const int y0 = (blk & 31) * 2;
    const int b  = blk >> 5;

    // ---- stage 4 rows x 66 px x 64 cin (16B chunks), XOR-swizzled ----
    for (int q = tid; q < 2112; q += 256) {
        const int c8 = q & 7;
        const int pr = q >> 3;          // 0..263
        const int px = pr % 66;
        const int r  = pr / 66;         // 0..3  (gy = y0-1+r)
        const int gy = y0 - 1 + r;
        const int gx = px - 1;
        uint4 v = {0u, 0u, 0u, 0u};
        if (gy >= 0 && gy < HH && gx >= 0 && gx < WW) {
            const int pix = b * HWSZ + gy * WW + gx;
            const int cin8 = c8 * 8;
            if (cin8 < xch) {
                v = *(const uint4*)(srcX + (size_t)pix * xch + cin8);
            } else if (cin8 < xch + 32) {
                if (!t0) v = *(const uint4*)(srcH + (size_t)pix * 32 + (cin8 - xch));
            }
        }
        lds4[(pr * 8 + c8) ^ (px & 7)] = v;
    }

    // ---- coalesced c-tile load: cbuf channel-major -> ctile[(yy*32+c)][p] ----
    // thread: row r = tid>>2 (yy = r>>5, c = r&31), 4 uint4 chunks q = j*4+(tid&3)
    const int fr  = tid >> 2;          // 0..63
    const int fyy = fr >> 5, fc = fr & 31;
    const size_t gflat = ((size_t)(b * HID + fc) * HH + (y0 + fyy)) * WW;
    if (!t0) {
#pragma unroll
        for (int j = 0; j < 4; ++j) {
            const int q = j * 4 + (tid & 3);   // uint4 idx 0..15 within row
            *(uint4*)(ctile + fr * CT_STRIDE + q * 4) =
                *(const uint4*)(cbuf + gflat + q * 4);
        }
    }
    __syncthreads();

    const int lane  = tid & 63;
    const int w     = tid >> 6;
    const int l15   = lane & 15, lhi = lane >> 4;
    const int khalf = w & 1;
    const int wrow  = w >> 1;           // which of the 2 output rows

    float bv[4];
#pragma unroll
    for (int n = 0; n < 4; ++n) bv[n] = bias[n * 32 + khalf * 16 + l15];
    f32x4 acc[4][4];
#pragma unroll
    for (int m = 0; m < 4; ++m)
#pragma unroll
        for (int n = 0; n < 4; ++n)
            acc[m][n] = (f32x4){bv[n], bv[n], bv[n], bv[n]};

    const int p0 = l15 + 1;   // tile px for dx=0, m=0
#pragma unroll
    for (int tap = 0; tap < 9; ++tap) {
        const int sr = wrow + tap / 3;  // staged row index for this ky
        const int dx = tap % 3 - 1;
#pragma unroll
        for (int kc = 0; kc < 2; ++kc) {
            const int kcell = kc * 4 + lhi;
            bf16x8 a[4];
#pragma unroll
            for (int m = 0; m < 4; ++m) {
                const int pxt = p0 + m * 16 + dx;
                a[m] = __builtin_bit_cast(bf16x8,
                        lds4[(((sr * 66 + pxt) * 8) + kcell) ^ (pxt & 7)]);
            }
#pragma unroll
            for (int n = 0; n < 4; ++n) {
                const bf16x8 bw = __builtin_bit_cast(bf16x8,
                        wf[((tap * 2 + kc) * 8 + (khalf + 2 * n)) * 64 + lane]);
#pragma unroll
                for (int m = 0; m < 4; ++m)
                    acc[m][n] = __builtin_amdgcn_mfma_f32_16x16x32_bf16(
                                    a[m], bw, acc[m][n], 0, 0, 0);
            }
        }
    }

    __syncthreads();                    // lds4 A-tile no longer needed
    float* htile = (float*)lds4;        // [64][CT_STRIDE] fp32 (17.4KB <= 33.8KB)

    // ---- LSTM pointwise epilogue (register -> LDS tiles) ----
    const int c = khalf * 16 + l15;                 // hid channel
    const int row = wrow * 32 + c;                  // transpose-tile row
    const size_t hb_base = ((size_t)b * HWSZ + (size_t)(y0 + wrow) * WW);
#pragma unroll
    for (int m = 0; m < 4; ++m) {
#pragma unroll
        for (int rr = 0; rr < 4; ++rr) {
            const int p = m * 16 + lhi * 4 + rr;
            const float cp = t0 ? 0.f : ctile[row * CT_STRIDE + p];
            const float iv = acc[m][0][rr], fv = acc[m][1][rr];
            const float ov = acc[m][2][rr], gv = acc[m][3][rr];
            const float ig = __builtin_amdgcn_rcpf(1.f + __expf(-iv));
            const float fg = __builtin_amdgcn_rcpf(1.f + __expf(-fv));
            const float og = __builtin_amdgcn_rcpf(1.f + __expf(-ov));
            const float gg = 1.f - 2.f * __builtin_amdgcn_rcpf(1.f + __expf(2.f * gv));
            const float cn = fg * cp + ig * gg;
            const float hn = og * (1.f - 2.f * __builtin_amdgcn_rcpf(1.f + __expf(2.f * cn)));
            ctile[row * CT_STRIDE + p] = cn;
            htile[row * CT_STRIDE + p] = hn;
            hbfo[(hb_base + p) * 32 + c] = f2bf(hn);
        }
    }
    __syncthreads();

    // ---- coalesced flush: htile -> hout(+hT), ctile -> cbuf ----
#pragma unroll
    for (int j = 0; j < 4; ++j) {
        const int q = j * 4 + (tid & 3);
        const uint4 hv = *(const uint4*)(htile + fr * CT_STRIDE + q * 4);
        const uint4 cv = *(const uint4*)(ctile + fr * CT_STRIDE + q * 4);
        *(uint4*)(hout + gflat + q * 4) = hv;
        *(uint4*)(cbuf + gflat + q * 4) = cv;
        if (hT) *(uint4*)(hT + gflat + q * 4) = hv;
    }
}

__global__ __launch_bounds__(256, 2)
void fused_step(
    const u16* srcX0, const u16* srcH0, const uint4* wf0, const float* bias0,
    float* cbuf0, float* hout0, float* hT0, u16* hbfo0, int t00, int act0,
    const u16* srcX1, const u16* srcH1, const uint4* wf1, const float* bias1,
    float* cbuf1, float* hout1, float* hT1, u16* hbfo1, int t01, int act1)
{
    __shared__ uint4 lds4[2112];              // 33,792 B (A-tile, then htile)
    __shared__ float ctile[64 * CT_STRIDE];   // 17,408 B
    const int blk = blockIdx.x;
    if (blk < 256) {
        if (!act0) return;
        conv_step(srcX0, 16, srcH0, wf0, bias0, cbuf0, hout0, hT0, hbfo0, t00, blk, lds4, ctile);
    } else {
        if (!act1) return;
        conv_step(srcX1, 32, srcH1, wf1, bias1, cbuf1, hout1, hT1, hbfo1, t01, blk - 256, lds4, ctile);
    }
}

extern "C" void kernel_launch(void* const* d_in, const int* in_sizes, int n_in,
                              void* d_out, int out_size, void* d_ws, size_t ws_size,
                              hipStream_t stream) {
    const float* x  = (const float*)d_in[0];
    const float* W0 = (const float*)d_in[1];
    const float* b0 = (const float*)d_in[2];
    const float* W1 = (const float*)d_in[3];
    const float* b1 = (const float*)d_in[4];
    float* out = (float*)d_out;

    float* hseq0 = out;
    float* hseq1 = out + 16777216;
    float* h0T   = out + 33554432;
    float* c0T   = out + 34603008;   // running c, layer 0 (channel-major, in-place)
    float* h1T   = out + 35651584;
    float* c1T   = out + 36700160;   // running c, layer 1

    // ws layout (bytes): xbf 16,777,216 | wf0 147,456 | wf1 147,456 |
    //                    hbf0[2] 2x2,097,152 | hbf1[2] 2x2,097,152  = 25.5 MB
    char* ws = (char*)d_ws;
    u16*  xbf = (u16*)ws;
    u16*  wf0 = (u16*)(ws + 16777216);
    u16*  wf1 = (u16*)(ws + 16777216 + 147456);
    u16*  hbf0[2] = { (u16*)(ws + 17072128), (u16*)(ws + 17072128 + 2097152) };
    u16*  hbf1[2] = { (u16*)(ws + 21266432), (u16*)(ws + 21266432 + 2097152) };

    prep_x<<<2048, 256, 0, stream>>>(x, xbf);
    prep_w<<<36, 256, 0, stream>>>(W0, wf0, 48);
    prep_w<<<36, 256, 0, stream>>>(W1, wf1, 64);

    const size_t hstep = (size_t)BATCH * HID * HWSZ;   // 1,048,576 floats
    const size_t xstep = (size_t)BATCH * HWSZ * 16;    // bf16 elems per t

    for (int d = 0; d <= TT; ++d) {
        const int t0 = (d < TT) ? d : TT - 1;      // clamped (inactive half)
        const int t1 = (d >= 1) ? d - 1 : 0;
        const int act0 = (d < TT), act1 = (d >= 1);
        fused_step<<<512, 256, 0, stream>>>(
            // layer 0, time t0: x = xbf[t0], h_prev = hbf0[(t0-1)&1]
            xbf + (size_t)t0 * xstep, hbf0[(t0 - 1) & 1],
            (const uint4*)wf0, b0, c0T,
            hseq0 + (size_t)t0 * hstep, (t0 == TT - 1 && act0) ? h0T : nullptr,
            hbf0[t0 & 1], (t0 == 0) ? 1 : 0, act0,
            // layer 1, time t1: x = hbf0[t1&1], h_prev = hbf1[(t1-1)&1]
            hbf0[t1 & 1], hbf1[(t1 - 1) & 1],
            (const uint4*)wf1, b1, c1T,
            hseq1 + (size_t)t1 * hstep, (t1 == TT - 1 && act1) ? h1T : nullptr,
            hbf1[t1 & 1], (t1 == 0) ? 1 : 0, act1);
    }
}